// Round 6
// baseline (341.963 us; speedup 1.0000x reference)
//
#include <hip/hip_runtime.h>
#include <hip/hip_bf16.h>
#include <stdint.h>

#define B_ 32
#define S_ 2048
#define H_ 1024
#define U_ 1024

typedef __attribute__((ext_vector_type(8))) short short8;
typedef __attribute__((ext_vector_type(4))) float f32x4;

#define AS1 __attribute__((address_space(1)))
#define AS3 __attribute__((address_space(3)))

__device__ __forceinline__ unsigned short f2bf(float f) {
  unsigned int u = __float_as_uint(f);
  u += 0x7fffu + ((u >> 16) & 1u);   // RNE
  return (unsigned short)(u >> 16);
}

// ---------- prep 0: values f32 -> bf16 copy ----------
__global__ void k_cvt(const float* __restrict__ v, unsigned short* __restrict__ o) {
  const size_t n = (size_t)B_ * S_ * H_;
  const size_t stride = (size_t)gridDim.x * blockDim.x * 8;
  for (size_t i = ((size_t)blockIdx.x * blockDim.x + threadIdx.x) * 8; i < n; i += stride) {
    float4 a = *(const float4*)(v + i), b = *(const float4*)(v + i + 4);
    short8 w;
    w[0]=f2bf(a.x); w[1]=f2bf(a.y); w[2]=f2bf(a.z); w[3]=f2bf(a.w);
    w[4]=f2bf(b.x); w[5]=f2bf(b.y); w[6]=f2bf(b.z); w[7]=f2bf(b.w);
    *(short8*)(o + i) = w;
  }
}

// ---------- prep 1: W1 [H][U] f32 -> W1T [U][H] bf16 ----------
__global__ void k_transpose_w1(const float* __restrict__ W1, unsigned short* __restrict__ W1T) {
  __shared__ float tile[64][65];
  const int tx = threadIdx.x, ty = threadIdx.y;
  const int u0 = blockIdx.x * 64, h0 = blockIdx.y * 64;
#pragma unroll
  for (int i = 0; i < 16; ++i) {
    int hl = ty + i * 4;
    tile[hl][tx] = W1[(size_t)(h0 + hl) * U_ + (u0 + tx)];
  }
  __syncthreads();
#pragma unroll
  for (int i = 0; i < 16; ++i) {
    int ul = ty + i * 4;
    W1T[(size_t)(u0 + ul) * H_ + (h0 + tx)] = f2bf(tile[tx][ul]);
  }
}

// ---------- prep 2: b1q[b][u] = b1[u] + b2[u] + query[b]@W2 ----------
__global__ void k_b1q(const float* __restrict__ query, const float* __restrict__ W2,
                      const float* __restrict__ b1, const float* __restrict__ b2,
                      float* __restrict__ b1q) {
  const int b = blockIdx.y;
  const int u = blockIdx.x * 256 + threadIdx.x;
  float acc = b1[u] + b2[u];
  const float* q = query + b * H_;
#pragma unroll 8
  for (int h = 0; h < H_; ++h) acc += q[h] * W2[(size_t)h * U_ + u];
  b1q[b * U_ + u] = acc;
}

// ---------- fused GEMM+tanh+V: m97 structure sized for 2 blocks/CU ----------
// Tile 128(BM, s-rows) x 256(BN, u-cols) x BK=32, 8 waves (2x4), wave-tile 64x64.
// acc = 16 f32x4 = 64 regs -> with launch_bounds(512,4) total <=128/wave
// -> 4 waves/SIMD = 2 blocks/CU co-resident (the m97/m114 latency-hiding mechanism).
// LDS 48 KB: As dbuf 2x[128r][32]bf16 = 16 KB, Bs dbuf 2x[256r][32] = 32 KB.
// Swizzle (r2-verified, 0 conflicts): 64-B rows of four 16-B chunks, logical chunk
// lc of row r at phys lc ^ ((r>>1)&3). Plain loop: prefetch t+1 at top via
// global_load_lds, read frags, 16 MFMA, one __syncthreads per step. No inline asm.
#define BM 128
#define BN 256
#define BK 32
#define NSTEP 32   // H_/BK

__global__ __launch_bounds__(512, 4)
void k_fused_score(const unsigned short* __restrict__ vbf,
                   const unsigned short* __restrict__ W1T,
                   const float* __restrict__ b1q, const float* __restrict__ V,
                   float* __restrict__ score_part) {
  __shared__ __align__(16) unsigned char smem[49152];
  unsigned short* As = (unsigned short*)smem;             // [2][128*32]
  unsigned short* Bs = (unsigned short*)(smem + 16384);   // [2][256*32]
  float* scorebuf = (float*)smem;                          // alias post-loop

  const int tid = threadIdx.x;
  const int g = blockIdx.x;                  // 2048 = 512 bm x 4 bn
  const int seq = (g & 7) * 256 + (g >> 3);  // bijective XCD swizzle (2048 = 8*256)
  const int bn = seq & 3;
  const int bm = seq >> 2;

  const int lane = tid & 63, wid = tid >> 6;
  const int wm = wid >> 2, wn = wid & 3;     // 2 x 4 waves
  const int u0 = bn * BN;

  // A staging: one 16B chunk per thread (8 KB tile). phys p = tid: row = p>>2,
  // phys chunk = p&3, logical chunk lc = (p&3) ^ ((row>>1)&3) -> pre-swizzled source.
  const int arow_s = tid >> 2;
  const int alc = (tid & 3) ^ ((arow_s >> 1) & 3);
  const unsigned short* aSrc = vbf + (size_t)(bm * BM + arow_s) * H_ + alc * 8;
  // B staging: two chunks per thread (16 KB tile). p0 = tid, p1 = 512+tid -> row+128, same lc.
  const unsigned short* bSrc0 = W1T + (size_t)(u0 + arow_s) * H_ + alc * 8;
  const unsigned short* bSrc1 = bSrc0 + (size_t)128 * H_;

  // fragment read swizzle: phys chunk = l16 ^ ((row>>1)&3), row = base + (lane&15)
  const int l15 = lane & 15, l16 = lane >> 4;
  const int fsq = ((l16 ^ ((lane >> 1) & 3)) << 3);   // shorts
  const int pA = (wm * 64 + l15) * 32 + fsq;          // + mf*512
  const int pB = (wn * 64 + l15) * 32 + fsq;          // + nf*512

  f32x4 acc[4][4];
#pragma unroll
  for (int mf = 0; mf < 4; ++mf)
#pragma unroll
    for (int nf = 0; nf < 4; ++nf) acc[mf][nf] = (f32x4){0.f, 0.f, 0.f, 0.f};

  // ---- prologue: stage tile 0 into buf 0 ----
  __builtin_amdgcn_global_load_lds((const AS1 void*)aSrc,
                                   (AS3 void*)&As[tid * 8], 16, 0, 0);
  __builtin_amdgcn_global_load_lds((const AS1 void*)bSrc0,
                                   (AS3 void*)&Bs[tid * 8], 16, 0, 0);
  __builtin_amdgcn_global_load_lds((const AS1 void*)bSrc1,
                                   (AS3 void*)&Bs[4096 + tid * 8], 16, 0, 0);
  __syncthreads();

  int cur = 0;
  for (int t = 0; t < NSTEP; ++t) {
    if (t + 1 < NSTEP) {                     // prefetch t+1 into buf^1
      const int ko = (t + 1) * BK;
      __builtin_amdgcn_global_load_lds((const AS1 void*)(aSrc + ko),
                                       (AS3 void*)&As[(cur ^ 1) * 4096 + tid * 8], 16, 0, 0);
      __builtin_amdgcn_global_load_lds((const AS1 void*)(bSrc0 + ko),
                                       (AS3 void*)&Bs[(cur ^ 1) * 8192 + tid * 8], 16, 0, 0);
      __builtin_amdgcn_global_load_lds((const AS1 void*)(bSrc1 + ko),
                                       (AS3 void*)&Bs[(cur ^ 1) * 8192 + 4096 + tid * 8], 16, 0, 0);
    }
    short8 af[4], bv[4];
#pragma unroll
    for (int mf = 0; mf < 4; ++mf)
      af[mf] = *(const short8*)&As[cur * 4096 + pA + mf * 512];
#pragma unroll
    for (int nf = 0; nf < 4; ++nf)
      bv[nf] = *(const short8*)&Bs[cur * 8192 + pB + nf * 512];
#pragma unroll
    for (int nf = 0; nf < 4; ++nf)
#pragma unroll
      for (int mf = 0; mf < 4; ++mf)
        acc[mf][nf] = __builtin_amdgcn_mfma_f32_16x16x32_bf16(af[mf], bv[nf], acc[mf][nf], 0, 0, 0);
    __syncthreads();                         // drains gl_lds for buf^1; other block covers
    cur ^= 1;
  }

  // ---- epilogue: tanh(acc + b1q) * V, reduce over u ----
  const int b_blk = bm >> 4;                 // 128-row tile never crosses a batch
  float bqv[4], vvv[4];
#pragma unroll
  for (int nf = 0; nf < 4; ++nf) {
    const int ug = u0 + wn * 64 + nf * 16 + l15;   // D col = lane&15
    bqv[nf] = b1q[b_blk * U_ + ug];
    vvv[nf] = V[ug];
  }
  float rp[4][4];
#pragma unroll
  for (int mf = 0; mf < 4; ++mf)
#pragma unroll
    for (int j = 0; j < 4; ++j) rp[mf][j] = 0.f;
#pragma unroll
  for (int nf = 0; nf < 4; ++nf)
#pragma unroll
    for (int mf = 0; mf < 4; ++mf) {
      const f32x4 c = acc[mf][nf];
#pragma unroll
      for (int j = 0; j < 4; ++j) {
        const float x = c[j] + bqv[nf];
        const float e = __expf(2.f * x);     // inf-safe tanh
        const float tt = 1.f - 2.f / (e + 1.f);
        rp[mf][j] += tt * vvv[nf];
      }
    }
#pragma unroll
  for (int mf = 0; mf < 4; ++mf)
#pragma unroll
    for (int j = 0; j < 4; ++j) {
      float v = rp[mf][j];
      v += __shfl_xor(v, 1);
      v += __shfl_xor(v, 2);
      v += __shfl_xor(v, 4);
      v += __shfl_xor(v, 8);
      rp[mf][j] = v;
    }
  if (l15 == 0) {
#pragma unroll
    for (int mf = 0; mf < 4; ++mf)
#pragma unroll
      for (int j = 0; j < 4; ++j)
        scorebuf[(wm * 64 + mf * 16 + l16 * 4 + j) * 4 + wn] = rp[mf][j];
  }
  __syncthreads();
  if (tid < BM) {
    const float s = scorebuf[tid * 4 + 0] + scorebuf[tid * 4 + 1] +
                    scorebuf[tid * 4 + 2] + scorebuf[tid * 4 + 3];
    score_part[(size_t)bn * (B_ * S_) + bm * BM + tid] = s;
  }
}

// ---------- softmax over S per batch (4 u-partials; bV shift-invariant -> dropped) ----------
__global__ void k_softmax(const float* __restrict__ sp, float* __restrict__ aw) {
  __shared__ float red[8];
  const int b = blockIdx.x, tid = threadIdx.x;   // 256 threads, 8 elems each
  const int BS = B_ * S_;
  float x[8];
  float m = -1e30f;
#pragma unroll
  for (int i = 0; i < 8; ++i) {
    const int s = b * S_ + tid + i * 256;
    x[i] = sp[s] + sp[BS + s] + sp[2 * BS + s] + sp[3 * BS + s];
    m = fmaxf(m, x[i]);
  }
#pragma unroll
  for (int off = 32; off; off >>= 1) m = fmaxf(m, __shfl_xor(m, off));
  if ((tid & 63) == 0) red[tid >> 6] = m;
  __syncthreads();
  m = fmaxf(fmaxf(red[0], red[1]), fmaxf(red[2], red[3]));
  float e[8];
  float sum = 0.f;
#pragma unroll
  for (int i = 0; i < 8; ++i) { e[i] = __expf(x[i] - m); sum += e[i]; }
#pragma unroll
  for (int off = 32; off; off >>= 1) sum += __shfl_xor(sum, off);
  __syncthreads();
  if ((tid & 63) == 0) red[4 + (tid >> 6)] = sum;
  __syncthreads();
  sum = red[4] + red[5] + red[6] + red[7];
  const float inv = 1.f / sum;
#pragma unroll
  for (int i = 0; i < 8; ++i) aw[b * S_ + tid + i * 256] = e[i] * inv;
}

// ---------- context: partial weighted sums over s-chunks, then combine ----------
__global__ void k_ctx_partial(const float* __restrict__ values, const float* __restrict__ aw,
                              float* __restrict__ part) {
  __shared__ float a_s[128];
  const int b = blockIdx.y, sc = blockIdx.x, tid = threadIdx.x;  // 16 chunks x 128 s
  if (tid < 128) a_s[tid] = aw[b * S_ + sc * 128 + tid];
  __syncthreads();
  const float4* vp = (const float4*)values + (size_t)(b * S_ + sc * 128) * (H_ / 4) + tid;
  float4 acc = {0.f, 0.f, 0.f, 0.f};
#pragma unroll 4
  for (int i = 0; i < 128; ++i) {
    const float4 v = vp[(size_t)i * (H_ / 4)];
    const float a = a_s[i];
    acc.x += a * v.x; acc.y += a * v.y; acc.z += a * v.z; acc.w += a * v.w;
  }
  ((float4*)part)[(size_t)(b * 16 + sc) * (H_ / 4) + tid] = acc;
}

__global__ void k_ctx_combine(const float* __restrict__ part, float* __restrict__ ctx) {
  const int b = blockIdx.x, tid = threadIdx.x;
  float4 s = {0.f, 0.f, 0.f, 0.f};
#pragma unroll
  for (int c = 0; c < 16; ++c) {
    const float4 v = ((const float4*)part)[(size_t)(b * 16 + c) * (H_ / 4) + tid];
    s.x += v.x; s.y += v.y; s.z += v.z; s.w += v.w;
  }
  ((float4*)ctx)[b * (H_ / 4) + tid] = s;
}

extern "C" void kernel_launch(void* const* d_in, const int* in_sizes, int n_in,
                              void* d_out, int out_size, void* d_ws, size_t ws_size,
                              hipStream_t stream) {
  const float* query  = (const float*)d_in[0];
  const float* values = (const float*)d_in[1];
  const float* W1     = (const float*)d_in[2];
  const float* b1     = (const float*)d_in[3];
  const float* W2     = (const float*)d_in[4];
  const float* b2     = (const float*)d_in[5];
  const float* V      = (const float*)d_in[6];
  // d_in[7] = bV: softmax shift-invariant, affects neither output -> unused.

  char* ws = (char*)d_ws;
  unsigned short* W1T = (unsigned short*)ws;                                   // 2 MB  [U][H] bf16
  float* b1q   = (float*)(ws + 2u * 1024u * 1024u);                            // 128 KB [B][U]
  float* spart = (float*)(ws + 2u * 1024u * 1024u + 128u * 1024u);             // 1 MB  [4][B*S]
  float* cpart = (float*)(ws + 2u * 1024u * 1024u + 128u * 1024u + 1024u * 1024u); // 2 MB
  unsigned short* vbf = (unsigned short*)(ws + 8u * 1024u * 1024u);            // 128 MB [B*S][H] bf16

  float* aw  = (float*)d_out;        // [B,S,1]
  float* ctx = aw + B_ * S_;         // [B,H]

  k_transpose_w1<<<dim3(16, 16), dim3(64, 4), 0, stream>>>(W1, W1T);
  k_b1q<<<dim3(4, 32), dim3(256), 0, stream>>>(query, W2, b1, b2, b1q);
  k_cvt<<<dim3(2048), dim3(256), 0, stream>>>(values, vbf);
  k_fused_score<<<dim3(2048), dim3(512), 0, stream>>>(vbf, W1T, b1q, V, spart);
  k_softmax<<<dim3(32), dim3(256), 0, stream>>>(spart, aw);
  k_ctx_partial<<<dim3(16, 32), dim3(256), 0, stream>>>(values, aw, cpart);
  k_ctx_combine<<<dim3(32), dim3(256), 0, stream>>>(cpart, ctx);
}

// Round 7
// 309.958 us; speedup vs baseline: 1.1033x; 1.1033x over previous
//
#include <hip/hip_runtime.h>
#include <hip/hip_bf16.h>
#include <stdint.h>

#define B_ 32
#define S_ 2048
#define H_ 1024
#define U_ 1024

typedef __attribute__((ext_vector_type(8))) short short8;
typedef __attribute__((ext_vector_type(4))) float f32x4;

#define AS1 __attribute__((address_space(1)))
#define AS3 __attribute__((address_space(3)))
#define FENCE __builtin_amdgcn_sched_barrier(0)

__device__ __forceinline__ unsigned short f2bf(float f) {
  unsigned int u = __float_as_uint(f);
  u += 0x7fffu + ((u >> 16) & 1u);   // RNE
  return (unsigned short)(u >> 16);
}
__device__ __forceinline__ float bf2f(unsigned short s) {
  return __uint_as_float(((unsigned int)s) << 16);
}

// ---------- prep 0: values f32 -> bf16 copy ----------
__global__ void k_cvt(const float* __restrict__ v, unsigned short* __restrict__ o) {
  const size_t n = (size_t)B_ * S_ * H_;
  const size_t stride = (size_t)gridDim.x * blockDim.x * 8;
  for (size_t i = ((size_t)blockIdx.x * blockDim.x + threadIdx.x) * 8; i < n; i += stride) {
    float4 a = *(const float4*)(v + i), b = *(const float4*)(v + i + 4);
    short8 w;
    w[0]=f2bf(a.x); w[1]=f2bf(a.y); w[2]=f2bf(a.z); w[3]=f2bf(a.w);
    w[4]=f2bf(b.x); w[5]=f2bf(b.y); w[6]=f2bf(b.z); w[7]=f2bf(b.w);
    *(short8*)(o + i) = w;
  }
}

// ---------- prep 1: W1 [H][U] f32 -> W1T [U][H] bf16 ----------
__global__ void k_transpose_w1(const float* __restrict__ W1, unsigned short* __restrict__ W1T) {
  __shared__ float tile[64][65];
  const int tx = threadIdx.x, ty = threadIdx.y;
  const int u0 = blockIdx.x * 64, h0 = blockIdx.y * 64;
#pragma unroll
  for (int i = 0; i < 16; ++i) {
    int hl = ty + i * 4;
    tile[hl][tx] = W1[(size_t)(h0 + hl) * U_ + (u0 + tx)];
  }
  __syncthreads();
#pragma unroll
  for (int i = 0; i < 16; ++i) {
    int ul = ty + i * 4;
    W1T[(size_t)(u0 + ul) * H_ + (h0 + tx)] = f2bf(tile[tx][ul]);
  }
}

// ---------- prep 2a: qpart[hs][b][u] = sum_{h in strip hs} query[b][h]*W2[h][u] ----------
// W2 read exactly once (4 MB) instead of once per batch.
__global__ void k_b1q_part(const float* __restrict__ query, const float* __restrict__ W2,
                           float* __restrict__ qpart) {
  __shared__ float q_sh[32 * 128];
  const int u = blockIdx.x * 256 + threadIdx.x;
  const int hs = blockIdx.y;                       // 8 strips of 128
  for (int i = threadIdx.x; i < 4096; i += 256) {
    const int b = i >> 7, h = i & 127;
    q_sh[i] = query[b * H_ + hs * 128 + h];
  }
  __syncthreads();
  float acc[32];
#pragma unroll
  for (int b = 0; b < 32; ++b) acc[b] = 0.f;
  for (int h = 0; h < 128; ++h) {
    const float w = W2[(size_t)(hs * 128 + h) * U_ + u];
#pragma unroll
    for (int b = 0; b < 32; ++b) acc[b] += q_sh[b * 128 + h] * w;
  }
#pragma unroll
  for (int b = 0; b < 32; ++b) qpart[((size_t)hs * 32 + b) * U_ + u] = acc[b];
}

// ---------- prep 2b: b1q[b][u] = b1[u]+b2[u]+sum_hs qpart ----------
__global__ void k_b1q_comb(const float* __restrict__ qpart, const float* __restrict__ b1,
                           const float* __restrict__ b2, float* __restrict__ b1q) {
  const int u = blockIdx.x * 256 + threadIdx.x;
  const int b = blockIdx.y;
  float s = b1[u] + b2[u];
#pragma unroll
  for (int hs = 0; hs < 8; ++hs) s += qpart[((size_t)hs * 32 + b) * U_ + u];
  b1q[b * U_ + u] = s;
}

// ---------- fused GEMM+tanh+V: r6 structure + 3-deep counted-vmcnt pipeline ----------
// Tile 128x256xBK32, 8 waves (2x4), wave 64x64, acc 64 regs + VGPR<=64 -> 4 waves/SIMD,
// 2 blocks/CU (LDS 72 KB). Triple-buffered slots; at step t: issue DMA for t+2 into
// slot (t+2)%3, read frags from slot t%3, MFMA, then s_waitcnt vmcnt(3) (t+1's loads
// retired FIFO, t+2's stay in flight) + raw s_barrier. Never vmcnt(0) in the loop (T4).
// Safety: reads of slot k are consumed by MFMA before slot-k's end barrier; slot k is
// only rewritten at step k+2 (after that barrier). Swizzle as r2 (0 conflicts).
#define BM 128
#define BN 256
#define BK 32
#define NSTEP 32   // H_/BK

__global__ __launch_bounds__(512, 4)
void k_fused_score(const unsigned short* __restrict__ vbf,
                   const unsigned short* __restrict__ W1T,
                   const float* __restrict__ b1q, const float* __restrict__ V,
                   float* __restrict__ score_part) {
  __shared__ __align__(16) unsigned char smem[73728];
  unsigned short* As = (unsigned short*)smem;             // [3][128*32] = 24 KB
  unsigned short* Bs = (unsigned short*)(smem + 24576);   // [3][256*32] = 48 KB
  float* scorebuf = (float*)smem;                          // alias post-loop

  const int tid = threadIdx.x;
  const int g = blockIdx.x;                  // 2048 = 512 bm x 4 bn
  const int seq = (g & 7) * 256 + (g >> 3);  // bijective XCD swizzle (2048 = 8*256)
  const int bn = seq & 3;
  const int bm = seq >> 2;

  const int lane = tid & 63, wid = tid >> 6;
  const int wm = wid >> 2, wn = wid & 3;     // 2 x 4 waves
  const int u0 = bn * BN;

  // staging: pre-swizzled source chunk (r2-verified involution)
  const int arow_s = tid >> 2;
  const int alc = (tid & 3) ^ ((arow_s >> 1) & 3);
  const unsigned short* aSrc = vbf + (size_t)(bm * BM + arow_s) * H_ + alc * 8;
  const unsigned short* bSrc0 = W1T + (size_t)(u0 + arow_s) * H_ + alc * 8;
  const unsigned short* bSrc1 = bSrc0 + (size_t)128 * H_;

  // fragment read swizzle
  const int l15 = lane & 15, l16 = lane >> 4;
  const int fsq = ((l16 ^ ((lane >> 1) & 3)) << 3);   // shorts
  const int pA = (wm * 64 + l15) * 32 + fsq;          // + mf*512
  const int pB = (wn * 64 + l15) * 32 + fsq;          // + nf*512

  f32x4 acc[4][4];
#pragma unroll
  for (int mf = 0; mf < 4; ++mf)
#pragma unroll
    for (int nf = 0; nf < 4; ++nf) acc[mf][nf] = (f32x4){0.f, 0.f, 0.f, 0.f};

#define STAGE(tt, slot) { \
    const int ko_ = (tt) * BK; \
    __builtin_amdgcn_global_load_lds((const AS1 void*)(aSrc + ko_), \
        (AS3 void*)&As[(slot) * 4096 + tid * 8], 16, 0, 0); \
    __builtin_amdgcn_global_load_lds((const AS1 void*)(bSrc0 + ko_), \
        (AS3 void*)&Bs[(slot) * 8192 + tid * 8], 16, 0, 0); \
    __builtin_amdgcn_global_load_lds((const AS1 void*)(bSrc1 + ko_), \
        (AS3 void*)&Bs[(slot) * 8192 + 4096 + tid * 8], 16, 0, 0); }

  // ---- prologue: stage tiles 0,1 into slots 0,1; wait only for tile 0 ----
  STAGE(0, 0);
  STAGE(1, 1);
  asm volatile("s_waitcnt vmcnt(3)" ::: "memory");
  FENCE;
  __builtin_amdgcn_s_barrier();

  int slot = 0;
  for (int t = 0; t < NSTEP; ++t) {
    const int nslot = (slot >= 1) ? slot - 1 : 2;   // (t+2)%3
    if (t + 2 < NSTEP) { STAGE(t + 2, nslot); }
    FENCE;
    short8 af[4], bv[4];
#pragma unroll
    for (int mf = 0; mf < 4; ++mf)
      af[mf] = *(const short8*)&As[slot * 4096 + pA + mf * 512];
#pragma unroll
    for (int nf = 0; nf < 4; ++nf)
      bv[nf] = *(const short8*)&Bs[slot * 8192 + pB + nf * 512];
#pragma unroll
    for (int nf = 0; nf < 4; ++nf)
#pragma unroll
      for (int mf = 0; mf < 4; ++mf)
        acc[mf][nf] = __builtin_amdgcn_mfma_f32_16x16x32_bf16(af[mf], bv[nf], acc[mf][nf], 0, 0, 0);
    FENCE;
    if (t + 2 < NSTEP) { asm volatile("s_waitcnt vmcnt(3)" ::: "memory"); }
    else               { asm volatile("s_waitcnt vmcnt(0)" ::: "memory"); }
    FENCE;
    __builtin_amdgcn_s_barrier();
    slot = (slot == 2) ? 0 : slot + 1;
  }

  // ---- epilogue: tanh(acc + b1q) * V, reduce over u ----
  __syncthreads();
  const int b_blk = bm >> 4;                 // 128-row tile never crosses a batch
  float bqv[4], vvv[4];
#pragma unroll
  for (int nf = 0; nf < 4; ++nf) {
    const int ug = u0 + wn * 64 + nf * 16 + l15;   // D col = lane&15
    bqv[nf] = b1q[b_blk * U_ + ug];
    vvv[nf] = V[ug];
  }
  float rp[4][4];
#pragma unroll
  for (int mf = 0; mf < 4; ++mf)
#pragma unroll
    for (int j = 0; j < 4; ++j) rp[mf][j] = 0.f;
#pragma unroll
  for (int nf = 0; nf < 4; ++nf)
#pragma unroll
    for (int mf = 0; mf < 4; ++mf) {
      const f32x4 c = acc[mf][nf];
#pragma unroll
      for (int j = 0; j < 4; ++j) {
        const float x = c[j] + bqv[nf];
        const float e = __expf(2.f * x);     // inf-safe tanh
        const float tt = 1.f - 2.f / (e + 1.f);
        rp[mf][j] += tt * vvv[nf];
      }
    }
#pragma unroll
  for (int mf = 0; mf < 4; ++mf)
#pragma unroll
    for (int j = 0; j < 4; ++j) {
      float v = rp[mf][j];
      v += __shfl_xor(v, 1);
      v += __shfl_xor(v, 2);
      v += __shfl_xor(v, 4);
      v += __shfl_xor(v, 8);
      rp[mf][j] = v;
    }
  if (l15 == 0) {
#pragma unroll
    for (int mf = 0; mf < 4; ++mf)
#pragma unroll
      for (int j = 0; j < 4; ++j)
        scorebuf[(wm * 64 + mf * 16 + l16 * 4 + j) * 4 + wn] = rp[mf][j];
  }
  __syncthreads();
  if (tid < BM) {
    const float s = scorebuf[tid * 4 + 0] + scorebuf[tid * 4 + 1] +
                    scorebuf[tid * 4 + 2] + scorebuf[tid * 4 + 3];
    score_part[(size_t)bn * (B_ * S_) + bm * BM + tid] = s;
  }
}

// ---------- softmax over S per batch (4 u-partials; bV shift-invariant -> dropped) ----------
__global__ void k_softmax(const float* __restrict__ sp, float* __restrict__ aw) {
  __shared__ float red[8];
  const int b = blockIdx.x, tid = threadIdx.x;   // 256 threads, 8 elems each
  const int BS = B_ * S_;
  float x[8];
  float m = -1e30f;
#pragma unroll
  for (int i = 0; i < 8; ++i) {
    const int s = b * S_ + tid + i * 256;
    x[i] = sp[s] + sp[BS + s] + sp[2 * BS + s] + sp[3 * BS + s];
    m = fmaxf(m, x[i]);
  }
#pragma unroll
  for (int off = 32; off; off >>= 1) m = fmaxf(m, __shfl_xor(m, off));
  if ((tid & 63) == 0) red[tid >> 6] = m;
  __syncthreads();
  m = fmaxf(fmaxf(red[0], red[1]), fmaxf(red[2], red[3]));
  float e[8];
  float sum = 0.f;
#pragma unroll
  for (int i = 0; i < 8; ++i) { e[i] = __expf(x[i] - m); sum += e[i]; }
#pragma unroll
  for (int off = 32; off; off >>= 1) sum += __shfl_xor(sum, off);
  __syncthreads();
  if ((tid & 63) == 0) red[4 + (tid >> 6)] = sum;
  __syncthreads();
  sum = red[4] + red[5] + red[6] + red[7];
  const float inv = 1.f / sum;
#pragma unroll
  for (int i = 0; i < 8; ++i) aw[b * S_ + tid + i * 256] = e[i] * inv;
}

// ---------- context: partial weighted sums over s-chunks (bf16 values), then combine ----------
__global__ void k_ctx_partial(const unsigned short* __restrict__ vbf, const float* __restrict__ aw,
                              float* __restrict__ part) {
  __shared__ float a_s[128];
  const int b = blockIdx.y, sc = blockIdx.x, tid = threadIdx.x;  // 16 chunks x 128 s
  if (tid < 128) a_s[tid] = aw[b * S_ + sc * 128 + tid];
  __syncthreads();
  const unsigned short* vp = vbf + (size_t)(b * S_ + sc * 128) * H_ + tid * 4;
  float4 acc = {0.f, 0.f, 0.f, 0.f};
#pragma unroll 4
  for (int i = 0; i < 128; ++i) {
    const ushort4 v = *(const ushort4*)(vp + (size_t)i * H_);
    const float a = a_s[i];
    acc.x += a * bf2f(v.x); acc.y += a * bf2f(v.y);
    acc.z += a * bf2f(v.z); acc.w += a * bf2f(v.w);
  }
  ((float4*)part)[(size_t)(b * 16 + sc) * (H_ / 4) + tid] = acc;
}

__global__ void k_ctx_combine(const float* __restrict__ part, float* __restrict__ ctx) {
  const int b = blockIdx.x, tid = threadIdx.x;
  float4 s = {0.f, 0.f, 0.f, 0.f};
#pragma unroll
  for (int c = 0; c < 16; ++c) {
    const float4 v = ((const float4*)part)[(size_t)(b * 16 + c) * (H_ / 4) + tid];
    s.x += v.x; s.y += v.y; s.z += v.z; s.w += v.w;
  }
  ((float4*)ctx)[b * (H_ / 4) + tid] = s;
}

extern "C" void kernel_launch(void* const* d_in, const int* in_sizes, int n_in,
                              void* d_out, int out_size, void* d_ws, size_t ws_size,
                              hipStream_t stream) {
  const float* query  = (const float*)d_in[0];
  const float* values = (const float*)d_in[1];
  const float* W1     = (const float*)d_in[2];
  const float* b1     = (const float*)d_in[3];
  const float* W2     = (const float*)d_in[4];
  const float* b2     = (const float*)d_in[5];
  const float* V      = (const float*)d_in[6];
  // d_in[7] = bV: softmax shift-invariant, affects neither output -> unused.

  char* ws = (char*)d_ws;
  unsigned short* W1T = (unsigned short*)ws;                                   // 2 MB  [U][H] bf16
  float* b1q   = (float*)(ws + 2u * 1024u * 1024u);                            // 128 KB [B][U]
  float* spart = (float*)(ws + 2u * 1024u * 1024u + 128u * 1024u);             // 1 MB  [4][B*S]
  float* cpart = (float*)(ws + 3u * 1024u * 1024u + 128u * 1024u);             // 2 MB  [B*16][H]
  float* qpart = (float*)(ws + 5u * 1024u * 1024u + 128u * 1024u);             // 1 MB  [8][B][U]
  unsigned short* vbf = (unsigned short*)(ws + 8u * 1024u * 1024u);            // 128 MB [B*S][H] bf16

  float* aw  = (float*)d_out;        // [B,S,1]
  float* ctx = aw + B_ * S_;         // [B,H]

  k_transpose_w1<<<dim3(16, 16), dim3(64, 4), 0, stream>>>(W1, W1T);
  k_b1q_part<<<dim3(4, 8), dim3(256), 0, stream>>>(query, W2, qpart);
  k_b1q_comb<<<dim3(4, 32), dim3(256), 0, stream>>>(qpart, b1, b2, b1q);
  k_cvt<<<dim3(2048), dim3(256), 0, stream>>>(values, vbf);
  k_fused_score<<<dim3(2048), dim3(512), 0, stream>>>(vbf, W1T, b1q, V, spart);
  k_softmax<<<dim3(32), dim3(256), 0, stream>>>(spart, aw);
  k_ctx_partial<<<dim3(16, 32), dim3(256), 0, stream>>>(vbf, aw, cpart);
  k_ctx_combine<<<dim3(32), dim3(256), 0, stream>>>(cpart, ctx);
}

// Round 8
// 285.357 us; speedup vs baseline: 1.1984x; 1.0862x over previous
//
#include <hip/hip_runtime.h>
#include <hip/hip_bf16.h>
#include <stdint.h>

#define B_ 32
#define S_ 2048
#define H_ 1024
#define U_ 1024

typedef __attribute__((ext_vector_type(8))) short short8;
typedef __attribute__((ext_vector_type(4))) float f32x4;

#define AS1 __attribute__((address_space(1)))
#define AS3 __attribute__((address_space(3)))
#define FENCE __builtin_amdgcn_sched_barrier(0)

__device__ __forceinline__ unsigned short f2bf(float f) {
  unsigned int u = __float_as_uint(f);
  u += 0x7fffu + ((u >> 16) & 1u);   // RNE
  return (unsigned short)(u >> 16);
}

// ---------- prep 1: W1 [H][U] f32 -> W1T [U][H] bf16 ----------
__global__ void k_transpose_w1(const float* __restrict__ W1, unsigned short* __restrict__ W1T) {
  __shared__ float tile[64][65];
  const int tx = threadIdx.x, ty = threadIdx.y;
  const int u0 = blockIdx.x * 64, h0 = blockIdx.y * 64;
#pragma unroll
  for (int i = 0; i < 16; ++i) {
    int hl = ty + i * 4;
    tile[hl][tx] = W1[(size_t)(h0 + hl) * U_ + (u0 + tx)];
  }
  __syncthreads();
#pragma unroll
  for (int i = 0; i < 16; ++i) {
    int ul = ty + i * 4;
    W1T[(size_t)(u0 + ul) * H_ + (h0 + tx)] = f2bf(tile[tx][ul]);
  }
}

// ---------- prep 2a: qpart[hs][b][u] = sum_{h in strip hs} query[b][h]*W2[h][u] ----------
__global__ void k_b1q_part(const float* __restrict__ query, const float* __restrict__ W2,
                           float* __restrict__ qpart) {
  __shared__ float q_sh[32 * 128];
  const int u = blockIdx.x * 256 + threadIdx.x;
  const int hs = blockIdx.y;                       // 8 strips of 128
  for (int i = threadIdx.x; i < 4096; i += 256) {
    const int b = i >> 7, h = i & 127;
    q_sh[i] = query[b * H_ + hs * 128 + h];
  }
  __syncthreads();
  float acc[32];
#pragma unroll
  for (int b = 0; b < 32; ++b) acc[b] = 0.f;
  for (int h = 0; h < 128; ++h) {
    const float w = W2[(size_t)(hs * 128 + h) * U_ + u];
#pragma unroll
    for (int b = 0; b < 32; ++b) acc[b] += q_sh[b * 128 + h] * w;
  }
#pragma unroll
  for (int b = 0; b < 32; ++b) qpart[((size_t)hs * 32 + b) * U_ + u] = acc[b];
}

// ---------- prep 2b: b1q[b][u] = b1[u]+b2[u]+sum_hs qpart ----------
__global__ void k_b1q_comb(const float* __restrict__ qpart, const float* __restrict__ b1,
                           const float* __restrict__ b2, float* __restrict__ b1q) {
  const int u = blockIdx.x * 256 + threadIdx.x;
  const int b = blockIdx.y;
  float s = b1[u] + b2[u];
#pragma unroll
  for (int hs = 0; hs < 8; ++hs) s += qpart[((size_t)hs * 32 + b) * U_ + u];
  b1q[b * U_ + u] = s;
}

// ---------- fused GEMM+tanh+V: r7 pipeline + in-register f32->bf16 A staging ----------
// Tile 128x256xBK32, 8 waves (2x4), 2 blocks/CU. LDS 64 KB: As 2x[128*32]bf16=16 KB,
// Bs 3x[256*32]bf16=48 KB. B staged by global_load_lds (3-deep, counted vmcnt);
// A staged via regs: issue 2x float4 f32 at top of step t (for t+1), cvt+ds_write after
// MFMA. A-loads issued BEFORE B-DMA each step, so post-MFMA vmcnt(2) retires A(t+1) and
// B(t+1) while keeping B(t+2)'s 2 loads in flight (never vmcnt(0) mid-loop).
// Swizzle (r2-verified, 0 conflicts): logical chunk lc of row r at phys lc ^ ((r>>1)&3).
#define BM 128
#define BN 256
#define BK 32
#define NSTEP 32   // H_/BK

__global__ __launch_bounds__(512, 4)
void k_fused_score(const float* __restrict__ values,
                   const unsigned short* __restrict__ W1T,
                   const float* __restrict__ b1q, const float* __restrict__ V,
                   float* __restrict__ score_part) {
  __shared__ __align__(16) unsigned char smem[65536];
  unsigned short* As = (unsigned short*)smem;             // [2][128*32]
  unsigned short* Bs = (unsigned short*)(smem + 16384);   // [3][256*32]
  float* scorebuf = (float*)smem;                          // alias post-loop

  const int tid = threadIdx.x;
  const int g = blockIdx.x;                  // 2048 = 512 bm x 4 bn
  const int seq = (g & 7) * 256 + (g >> 3);  // bijective XCD swizzle (2048 = 8*256)
  const int bn = seq & 3;
  const int bm = seq >> 2;

  const int lane = tid & 63, wid = tid >> 6;
  const int wm = wid >> 2, wn = wid & 3;     // 2 x 4 waves
  const int u0 = bn * BN;

  // A staging (regs): thread -> (row, logical chunk of 8 bf16)
  const int arow = tid >> 2;                 // 0..127
  const int alc  = tid & 3;                  // logical chunk
  const int aplc = alc ^ ((arow >> 1) & 3);  // phys chunk (swizzled)
  const float* aSrcF = values + (size_t)(bm * BM + arow) * H_ + alc * 8;
  const int awoff = arow * 32 + aplc * 8;    // shorts, + slot*4096

  // B staging (gl_lds, pre-swizzled source)
  const int blc = (tid & 3) ^ ((arow >> 1) & 3);
  const unsigned short* bSrc0 = W1T + (size_t)(u0 + arow) * H_ + blc * 8;
  const unsigned short* bSrc1 = bSrc0 + (size_t)128 * H_;

  // fragment read swizzle
  const int l15 = lane & 15, l16 = lane >> 4;
  const int fsq = ((l16 ^ ((lane >> 1) & 3)) << 3);   // shorts
  const int pA = (wm * 64 + l15) * 32 + fsq;          // + mf*512
  const int pB = (wn * 64 + l15) * 32 + fsq;          // + nf*512

  f32x4 acc[4][4];
#pragma unroll
  for (int mf = 0; mf < 4; ++mf)
#pragma unroll
    for (int nf = 0; nf < 4; ++nf) acc[mf][nf] = (f32x4){0.f, 0.f, 0.f, 0.f};

  float4 ar0, ar1;

#define ISSUE_ARF(tt) { \
    const float4* p_ = (const float4*)(aSrcF + (tt) * BK); \
    ar0 = p_[0]; ar1 = p_[1]; }

#define WRITE_ARF(slot) { \
    short8 w_; \
    w_[0]=f2bf(ar0.x); w_[1]=f2bf(ar0.y); w_[2]=f2bf(ar0.z); w_[3]=f2bf(ar0.w); \
    w_[4]=f2bf(ar1.x); w_[5]=f2bf(ar1.y); w_[6]=f2bf(ar1.z); w_[7]=f2bf(ar1.w); \
    *(short8*)&As[(slot) * 4096 + awoff] = w_; }

#define STAGE_B(tt, slot) { \
    const int ko_ = (tt) * BK; \
    __builtin_amdgcn_global_load_lds((const AS1 void*)(bSrc0 + ko_), \
        (AS3 void*)&Bs[(slot) * 8192 + tid * 8], 16, 0, 0); \
    __builtin_amdgcn_global_load_lds((const AS1 void*)(bSrc1 + ko_), \
        (AS3 void*)&Bs[(slot) * 8192 + 4096 + tid * 8], 16, 0, 0); }

  // ---- prologue: A(0)->regs->LDS slot0; B(0),B(1) DMA -> slots 0,1 ----
  ISSUE_ARF(0);                                // 2 loads (oldest)
  STAGE_B(0, 0);                               // 2 gl_lds
  STAGE_B(1, 1);                               // 2 gl_lds
  asm volatile("s_waitcnt vmcnt(4)" ::: "memory");   // A(0) done
  WRITE_ARF(0);
  asm volatile("s_waitcnt vmcnt(2)" ::: "memory");   // B(0) done; B(1) in flight
  asm volatile("s_waitcnt lgkmcnt(0)" ::: "memory");
  FENCE;
  __builtin_amdgcn_s_barrier();

  for (int t = 0; t < NSTEP; ++t) {
    const int aslot = t & 1;
    const int bslot = t % 3;
    if (t + 1 < NSTEP) { ISSUE_ARF(t + 1); }           // A first (retires at vmcnt(2))
    if (t + 2 < NSTEP) { STAGE_B(t + 2, (t + 2) % 3); } // B(t+2) stays in flight
    FENCE;
    short8 af[4], bv[4];
#pragma unroll
    for (int mf = 0; mf < 4; ++mf)
      af[mf] = *(const short8*)&As[aslot * 4096 + pA + mf * 512];
#pragma unroll
    for (int nf = 0; nf < 4; ++nf)
      bv[nf] = *(const short8*)&Bs[bslot * 8192 + pB + nf * 512];
#pragma unroll
    for (int nf = 0; nf < 4; ++nf)
#pragma unroll
      for (int mf = 0; mf < 4; ++mf)
        acc[mf][nf] = __builtin_amdgcn_mfma_f32_16x16x32_bf16(af[mf], bv[nf], acc[mf][nf], 0, 0, 0);
    FENCE;
    if (t + 2 < NSTEP)      { asm volatile("s_waitcnt vmcnt(2)" ::: "memory"); }
    else                    { asm volatile("s_waitcnt vmcnt(0)" ::: "memory"); }
    if (t + 1 < NSTEP) { WRITE_ARF((t + 1) & 1); }
    asm volatile("s_waitcnt lgkmcnt(0)" ::: "memory");
    FENCE;
    __builtin_amdgcn_s_barrier();
  }

  // ---- epilogue: tanh(acc + b1q) * V, reduce over u ----
  __syncthreads();
  const int b_blk = bm >> 4;                 // 128-row tile never crosses a batch
  float bqv[4], vvv[4];
#pragma unroll
  for (int nf = 0; nf < 4; ++nf) {
    const int ug = u0 + wn * 64 + nf * 16 + l15;   // D col = lane&15
    bqv[nf] = b1q[b_blk * U_ + ug];
    vvv[nf] = V[ug];
  }
  float rp[4][4];
#pragma unroll
  for (int mf = 0; mf < 4; ++mf)
#pragma unroll
    for (int j = 0; j < 4; ++j) rp[mf][j] = 0.f;
#pragma unroll
  for (int nf = 0; nf < 4; ++nf)
#pragma unroll
    for (int mf = 0; mf < 4; ++mf) {
      const f32x4 c = acc[mf][nf];
#pragma unroll
      for (int j = 0; j < 4; ++j) {
        const float x = c[j] + bqv[nf];
        const float e = __expf(2.f * x);     // inf-safe tanh
        const float tt = 1.f - 2.f / (e + 1.f);
        rp[mf][j] += tt * vvv[nf];
      }
    }
#pragma unroll
  for (int mf = 0; mf < 4; ++mf)
#pragma unroll
    for (int j = 0; j < 4; ++j) {
      float v = rp[mf][j];
      v += __shfl_xor(v, 1);
      v += __shfl_xor(v, 2);
      v += __shfl_xor(v, 4);
      v += __shfl_xor(v, 8);
      rp[mf][j] = v;
    }
  if (l15 == 0) {
#pragma unroll
    for (int mf = 0; mf < 4; ++mf)
#pragma unroll
      for (int j = 0; j < 4; ++j)
        scorebuf[(wm * 64 + mf * 16 + l16 * 4 + j) * 4 + wn] = rp[mf][j];
  }
  __syncthreads();
  if (tid < BM) {
    const float s = scorebuf[tid * 4 + 0] + scorebuf[tid * 4 + 1] +
                    scorebuf[tid * 4 + 2] + scorebuf[tid * 4 + 3];
    score_part[(size_t)bn * (B_ * S_) + bm * BM + tid] = s;
  }
}

// ---------- softmax over S per batch (4 u-partials; bV shift-invariant -> dropped) ----------
__global__ void k_softmax(const float* __restrict__ sp, float* __restrict__ aw) {
  __shared__ float red[8];
  const int b = blockIdx.x, tid = threadIdx.x;   // 256 threads, 8 elems each
  const int BS = B_ * S_;
  float x[8];
  float m = -1e30f;
#pragma unroll
  for (int i = 0; i < 8; ++i) {
    const int s = b * S_ + tid + i * 256;
    x[i] = sp[s] + sp[BS + s] + sp[2 * BS + s] + sp[3 * BS + s];
    m = fmaxf(m, x[i]);
  }
#pragma unroll
  for (int off = 32; off; off >>= 1) m = fmaxf(m, __shfl_xor(m, off));
  if ((tid & 63) == 0) red[tid >> 6] = m;
  __syncthreads();
  m = fmaxf(fmaxf(red[0], red[1]), fmaxf(red[2], red[3]));
  float e[8];
  float sum = 0.f;
#pragma unroll
  for (int i = 0; i < 8; ++i) { e[i] = __expf(x[i] - m); sum += e[i]; }
#pragma unroll
  for (int off = 32; off; off >>= 1) sum += __shfl_xor(sum, off);
  __syncthreads();
  if ((tid & 63) == 0) red[4 + (tid >> 6)] = sum;
  __syncthreads();
  sum = red[4] + red[5] + red[6] + red[7];
  const float inv = 1.f / sum;
#pragma unroll
  for (int i = 0; i < 8; ++i) aw[b * S_ + tid + i * 256] = e[i] * inv;
}

// ---------- context: partial weighted sums over 64-row s-chunks (f32), then combine ----------
__global__ void k_ctx_partial(const float* __restrict__ values, const float* __restrict__ aw,
                              float* __restrict__ part) {
  __shared__ float a_s[64];
  const int b = blockIdx.y, sc = blockIdx.x, tid = threadIdx.x;  // 32 chunks x 64 s
  if (tid < 64) a_s[tid] = aw[b * S_ + sc * 64 + tid];
  __syncthreads();
  const float4* vp = (const float4*)values + (size_t)(b * S_ + sc * 64) * (H_ / 4) + tid;
  float4 acc = {0.f, 0.f, 0.f, 0.f};
#pragma unroll 4
  for (int i = 0; i < 64; ++i) {
    const float4 v = vp[(size_t)i * (H_ / 4)];
    const float a = a_s[i];
    acc.x += a * v.x; acc.y += a * v.y; acc.z += a * v.z; acc.w += a * v.w;
  }
  ((float4*)part)[(size_t)(b * 32 + sc) * (H_ / 4) + tid] = acc;
}

__global__ void k_ctx_combine(const float* __restrict__ part, float* __restrict__ ctx) {
  const int b = blockIdx.x, tid = threadIdx.x;
  float4 s = {0.f, 0.f, 0.f, 0.f};
#pragma unroll
  for (int c = 0; c < 32; ++c) {
    const float4 v = ((const float4*)part)[(size_t)(b * 32 + c) * (H_ / 4) + tid];
    s.x += v.x; s.y += v.y; s.z += v.z; s.w += v.w;
  }
  ((float4*)ctx)[b * (H_ / 4) + tid] = s;
}

extern "C" void kernel_launch(void* const* d_in, const int* in_sizes, int n_in,
                              void* d_out, int out_size, void* d_ws, size_t ws_size,
                              hipStream_t stream) {
  const float* query  = (const float*)d_in[0];
  const float* values = (const float*)d_in[1];
  const float* W1     = (const float*)d_in[2];
  const float* b1     = (const float*)d_in[3];
  const float* W2     = (const float*)d_in[4];
  const float* b2     = (const float*)d_in[5];
  const float* V      = (const float*)d_in[6];
  // d_in[7] = bV: softmax shift-invariant, affects neither output -> unused.

  char* ws = (char*)d_ws;
  unsigned short* W1T = (unsigned short*)ws;                                   // 2 MB  [U][H] bf16
  float* b1q   = (float*)(ws + 2u * 1024u * 1024u);                            // 128 KB [B][U]
  float* spart = (float*)(ws + 2u * 1024u * 1024u + 128u * 1024u);             // 1 MB  [4][B*S]
  float* qpart = (float*)(ws + 3u * 1024u * 1024u + 128u * 1024u);             // 1 MB  [8][B][U]
  float* cpart = (float*)(ws + 4u * 1024u * 1024u + 256u * 1024u);             // 4 MB  [B*32][H]

  float* aw  = (float*)d_out;        // [B,S,1]
  float* ctx = aw + B_ * S_;         // [B,H]

  k_transpose_w1<<<dim3(16, 16), dim3(64, 4), 0, stream>>>(W1, W1T);
  k_b1q_part<<<dim3(4, 8), dim3(256), 0, stream>>>(query, W2, qpart);
  k_b1q_comb<<<dim3(4, 32), dim3(256), 0, stream>>>(qpart, b1, b2, b1q);
  k_fused_score<<<dim3(2048), dim3(512), 0, stream>>>(values, W1T, b1q, V, spart);
  k_softmax<<<dim3(32), dim3(256), 0, stream>>>(spart, aw);
  k_ctx_partial<<<dim3(32, 32), dim3(256), 0, stream>>>(values, aw, cpart);
  k_ctx_combine<<<dim3(32), dim3(256), 0, stream>>>(cpart, ctx);
}

// Round 9
// 283.459 us; speedup vs baseline: 1.2064x; 1.0067x over previous
//
#include <hip/hip_runtime.h>
#include <hip/hip_bf16.h>
#include <stdint.h>

#define B_ 32
#define S_ 2048
#define H_ 1024
#define U_ 1024

typedef __attribute__((ext_vector_type(8))) short short8;
typedef __attribute__((ext_vector_type(4))) float f32x4;

#define AS1 __attribute__((address_space(1)))
#define AS3 __attribute__((address_space(3)))
#define FENCE __builtin_amdgcn_sched_barrier(0)

__device__ __forceinline__ unsigned short f2bf(float f) {
  unsigned int u = __float_as_uint(f);
  u += 0x7fffu + ((u >> 16) & 1u);   // RNE
  return (unsigned short)(u >> 16);
}

// ---------- prep 1: W1 [H][U] f32 -> W1T [U][H] bf16 ----------
__global__ void k_transpose_w1(const float* __restrict__ W1, unsigned short* __restrict__ W1T) {
  __shared__ float tile[64][65];
  const int tx = threadIdx.x, ty = threadIdx.y;
  const int u0 = blockIdx.x * 64, h0 = blockIdx.y * 64;
#pragma unroll
  for (int i = 0; i < 16; ++i) {
    int hl = ty + i * 4;
    tile[hl][tx] = W1[(size_t)(h0 + hl) * U_ + (u0 + tx)];
  }
  __syncthreads();
#pragma unroll
  for (int i = 0; i < 16; ++i) {
    int ul = ty + i * 4;
    W1T[(size_t)(u0 + ul) * H_ + (h0 + tx)] = f2bf(tile[tx][ul]);
  }
}

// ---------- prep 2a: qpart[hs][b][u] = sum_{h in strip hs} query[b][h]*W2[h][u] ----------
__global__ void k_b1q_part(const float* __restrict__ query, const float* __restrict__ W2,
                           float* __restrict__ qpart) {
  __shared__ float q_sh[32 * 128];
  const int u = blockIdx.x * 256 + threadIdx.x;
  const int hs = blockIdx.y;                       // 8 strips of 128
  for (int i = threadIdx.x; i < 4096; i += 256) {
    const int b = i >> 7, h = i & 127;
    q_sh[i] = query[b * H_ + hs * 128 + h];
  }
  __syncthreads();
  float acc[32];
#pragma unroll
  for (int b = 0; b < 32; ++b) acc[b] = 0.f;
  for (int h = 0; h < 128; ++h) {
    const float w = W2[(size_t)(hs * 128 + h) * U_ + u];
#pragma unroll
    for (int b = 0; b < 32; ++b) acc[b] += q_sh[b * 128 + h] * w;
  }
#pragma unroll
  for (int b = 0; b < 32; ++b) qpart[((size_t)hs * 32 + b) * U_ + u] = acc[b];
}

// ---------- prep 2b: b1q[b][u] = b1[u]+b2[u]+sum_hs qpart ----------
__global__ void k_b1q_comb(const float* __restrict__ qpart, const float* __restrict__ b1,
                           const float* __restrict__ b2, float* __restrict__ b1q) {
  const int u = blockIdx.x * 256 + threadIdx.x;
  const int b = blockIdx.y;
  float s = b1[u] + b2[u];
#pragma unroll
  for (int hs = 0; hs < 8; ++hs) s += qpart[((size_t)hs * 32 + b) * U_ + u];
  b1q[b * U_ + u] = s;
}

// ---------- fused GEMM+tanh+V: 2-step-deep pipeline for BOTH operands ----------
// Tile 128x256xBK32, 8 waves (2x4), 2 blocks/CU, LDS 64 KB (As 2x8KB, Bs 3x16KB).
// Step t: issue A(t+2)->regset[t&1] THEN B(t+2) gl_lds; frags+MFMA on tile t;
// vmcnt(4) retires exactly A(t+1)+B(t+1) (FIFO: A(t+1),B(t+1) older than t+2's 4 loads);
// write A(t+1) regset[(t+1)&1] -> As[(t+1)&1]; lgkm0; barrier. Never vmcnt(0) mid-loop.
// Loop unrolled x2 so reg-set selection is compile-time (no scratch).
// Swizzle (0 conflicts, r2-verified): chunk lc of row r at phys lc ^ ((r>>1)&3).
#define BM 128
#define BN 256
#define BK 32
#define NSTEP 32   // H_/BK

__global__ __launch_bounds__(512, 4)
void k_fused_score(const float* __restrict__ values,
                   const unsigned short* __restrict__ W1T,
                   const float* __restrict__ b1q, const float* __restrict__ V,
                   float* __restrict__ score_part) {
  __shared__ __align__(16) unsigned char smem[65536];
  unsigned short* As = (unsigned short*)smem;             // [2][128*32]
  unsigned short* Bs = (unsigned short*)(smem + 16384);   // [3][256*32]
  float* scorebuf = (float*)smem;                          // alias post-loop

  const int tid = threadIdx.x;
  const int g = blockIdx.x;                  // 2048 = 512 bm x 4 bn
  const int seq = (g & 7) * 256 + (g >> 3);  // bijective XCD swizzle (2048 = 8*256)
  const int bn = seq & 3;
  const int bm = seq >> 2;

  const int lane = tid & 63, wid = tid >> 6;
  const int wm = wid >> 2, wn = wid & 3;     // 2 x 4 waves
  const int u0 = bn * BN;

  // A staging (regs): thread -> (row, logical chunk of 8 f32->bf16)
  const int arow = tid >> 2;                 // 0..127
  const int alc  = tid & 3;                  // logical chunk
  const int aplc = alc ^ ((arow >> 1) & 3);  // phys chunk (swizzled)
  const float* aSrcF = values + (size_t)(bm * BM + arow) * H_ + alc * 8;
  const int awoff = arow * 32 + aplc * 8;    // shorts, + slot*4096

  // B staging (gl_lds, pre-swizzled source)
  const unsigned short* bSrc0 = W1T + (size_t)(u0 + arow) * H_ + aplc * 8;
  const unsigned short* bSrc1 = bSrc0 + (size_t)128 * H_;

  // fragment read swizzle
  const int l15 = lane & 15, l16 = lane >> 4;
  const int fsq = ((l16 ^ ((lane >> 1) & 3)) << 3);   // shorts
  const int pA = (wm * 64 + l15) * 32 + fsq;          // + mf*512
  const int pB = (wn * 64 + l15) * 32 + fsq;          // + nf*512

  f32x4 acc[4][4];
#pragma unroll
  for (int mf = 0; mf < 4; ++mf)
#pragma unroll
    for (int nf = 0; nf < 4; ++nf) acc[mf][nf] = (f32x4){0.f, 0.f, 0.f, 0.f};

  float4 aX0, aX1, aY0, aY1;                 // two A reg-sets (compile-time selected)

#define ISSUE_SET(P0, P1, tt) { \
    const float4* p_ = (const float4*)(aSrcF + (tt) * BK); \
    P0 = p_[0]; P1 = p_[1]; }

#define WRITE_SET(P0, P1, slot) { \
    short8 w_; \
    w_[0]=f2bf(P0.x); w_[1]=f2bf(P0.y); w_[2]=f2bf(P0.z); w_[3]=f2bf(P0.w); \
    w_[4]=f2bf(P1.x); w_[5]=f2bf(P1.y); w_[6]=f2bf(P1.z); w_[7]=f2bf(P1.w); \
    *(short8*)&As[(slot) * 4096 + awoff] = w_; }

#define STAGE_B(tt, slot) { \
    const int ko_ = (tt) * BK; \
    __builtin_amdgcn_global_load_lds((const AS1 void*)(bSrc0 + ko_), \
        (AS3 void*)&Bs[(slot) * 8192 + tid * 8], 16, 0, 0); \
    __builtin_amdgcn_global_load_lds((const AS1 void*)(bSrc1 + ko_), \
        (AS3 void*)&Bs[(slot) * 8192 + 4096 + tid * 8], 16, 0, 0); }

  // One sub-step of the K-loop. ASLOT = T&1 (compile-time within unrolled pair).
#define SUBSTEP(T, ASLOT, RI0, RI1, RW0, RW1) { \
    if ((T) + 2 < NSTEP) { \
      ISSUE_SET(RI0, RI1, (T) + 2); \
      STAGE_B((T) + 2, ((T) + 2) % 3); \
    } \
    FENCE; \
    short8 af[4], bv[4]; \
    const int bO_ = ((T) % 3) * 8192; \
    _Pragma("unroll") \
    for (int mf = 0; mf < 4; ++mf) \
      af[mf] = *(const short8*)&As[(ASLOT) * 4096 + pA + mf * 512]; \
    _Pragma("unroll") \
    for (int nf = 0; nf < 4; ++nf) \
      bv[nf] = *(const short8*)&Bs[bO_ + pB + nf * 512]; \
    _Pragma("unroll") \
    for (int nf = 0; nf < 4; ++nf) \
      _Pragma("unroll") \
      for (int mf = 0; mf < 4; ++mf) \
        acc[mf][nf] = __builtin_amdgcn_mfma_f32_16x16x32_bf16(af[mf], bv[nf], acc[mf][nf], 0, 0, 0); \
    FENCE; \
    if ((T) + 2 < NSTEP) { asm volatile("s_waitcnt vmcnt(4)" ::: "memory"); } \
    else                 { asm volatile("s_waitcnt vmcnt(0)" ::: "memory"); } \
    if ((T) + 1 < NSTEP) { WRITE_SET(RW0, RW1, ((T) + 1) & 1); } \
    asm volatile("s_waitcnt lgkmcnt(0)" ::: "memory"); \
    FENCE; \
    __builtin_amdgcn_s_barrier(); }

  // ---- prologue: A(0)->X, A(1)->Y, B(0)->slot0, B(1)->slot1 ----
  ISSUE_SET(aX0, aX1, 0);                       // 2 loads (oldest)
  ISSUE_SET(aY0, aY1, 1);                       // 2 loads
  STAGE_B(0, 0);                                // 2 gl_lds
  STAGE_B(1, 1);                                // 2 gl_lds
  asm volatile("s_waitcnt vmcnt(6)" ::: "memory");   // A(0) done
  WRITE_SET(aX0, aX1, 0);
  asm volatile("s_waitcnt vmcnt(2)" ::: "memory");   // A(1)+B(0) done; B(1) in flight
  asm volatile("s_waitcnt lgkmcnt(0)" ::: "memory");
  FENCE;
  __builtin_amdgcn_s_barrier();

  for (int t = 0; t < NSTEP; t += 2) {
    // even sub-step: issue A(t+2)->X, write A(t+1) from Y
    SUBSTEP(t,     0, aX0, aX1, aY0, aY1);
    // odd sub-step: issue A(t+3)->Y, write A(t+2) from X
    SUBSTEP(t + 1, 1, aY0, aY1, aX0, aX1);
  }

  // ---- epilogue: tanh(acc + b1q) * V, reduce over u ----
  __syncthreads();
  const int b_blk = bm >> 4;                 // 128-row tile never crosses a batch
  float bqv[4], vvv[4];
#pragma unroll
  for (int nf = 0; nf < 4; ++nf) {
    const int ug = u0 + wn * 64 + nf * 16 + l15;   // D col = lane&15
    bqv[nf] = b1q[b_blk * U_ + ug];
    vvv[nf] = V[ug];
  }
  float rp[4][4];
#pragma unroll
  for (int mf = 0; mf < 4; ++mf)
#pragma unroll
    for (int j = 0; j < 4; ++j) rp[mf][j] = 0.f;
#pragma unroll
  for (int nf = 0; nf < 4; ++nf)
#pragma unroll
    for (int mf = 0; mf < 4; ++mf) {
      const f32x4 c = acc[mf][nf];
#pragma unroll
      for (int j = 0; j < 4; ++j) {
        const float x = c[j] + bqv[nf];
        const float e = __expf(2.f * x);     // inf-safe tanh
        const float tt = 1.f - 2.f / (e + 1.f);
        rp[mf][j] += tt * vvv[nf];
      }
    }
#pragma unroll
  for (int mf = 0; mf < 4; ++mf)
#pragma unroll
    for (int j = 0; j < 4; ++j) {
      float v = rp[mf][j];
      v += __shfl_xor(v, 1);
      v += __shfl_xor(v, 2);
      v += __shfl_xor(v, 4);
      v += __shfl_xor(v, 8);
      rp[mf][j] = v;
    }
  if (l15 == 0) {
#pragma unroll
    for (int mf = 0; mf < 4; ++mf)
#pragma unroll
      for (int j = 0; j < 4; ++j)
        scorebuf[(wm * 64 + mf * 16 + l16 * 4 + j) * 4 + wn] = rp[mf][j];
  }
  __syncthreads();
  if (tid < BM) {
    const float s = scorebuf[tid * 4 + 0] + scorebuf[tid * 4 + 1] +
                    scorebuf[tid * 4 + 2] + scorebuf[tid * 4 + 3];
    score_part[(size_t)bn * (B_ * S_) + bm * BM + tid] = s;
  }
}

// ---------- softmax over S per batch (4 u-partials; bV shift-invariant -> dropped) ----------
__global__ void k_softmax(const float* __restrict__ sp, float* __restrict__ aw) {
  __shared__ float red[8];
  const int b = blockIdx.x, tid = threadIdx.x;   // 256 threads, 8 elems each
  const int BS = B_ * S_;
  float x[8];
  float m = -1e30f;
#pragma unroll
  for (int i = 0; i < 8; ++i) {
    const int s = b * S_ + tid + i * 256;
    x[i] = sp[s] + sp[BS + s] + sp[2 * BS + s] + sp[3 * BS + s];
    m = fmaxf(m, x[i]);
  }
#pragma unroll
  for (int off = 32; off; off >>= 1) m = fmaxf(m, __shfl_xor(m, off));
  if ((tid & 63) == 0) red[tid >> 6] = m;
  __syncthreads();
  m = fmaxf(fmaxf(red[0], red[1]), fmaxf(red[2], red[3]));
  float e[8];
  float sum = 0.f;
#pragma unroll
  for (int i = 0; i < 8; ++i) { e[i] = __expf(x[i] - m); sum += e[i]; }
#pragma unroll
  for (int off = 32; off; off >>= 1) sum += __shfl_xor(sum, off);
  __syncthreads();
  if ((tid & 63) == 0) red[4 + (tid >> 6)] = sum;
  __syncthreads();
  sum = red[4] + red[5] + red[6] + red[7];
  const float inv = 1.f / sum;
#pragma unroll
  for (int i = 0; i < 8; ++i) aw[b * S_ + tid + i * 256] = e[i] * inv;
}

// ---------- context: partial weighted sums over 64-row s-chunks (f32), then combine ----------
__global__ void k_ctx_partial(const float* __restrict__ values, const float* __restrict__ aw,
                              float* __restrict__ part) {
  __shared__ float a_s[64];
  const int b = blockIdx.y, sc = blockIdx.x, tid = threadIdx.x;  // 32 chunks x 64 s
  if (tid < 64) a_s[tid] = aw[b * S_ + sc * 64 + tid];
  __syncthreads();
  const float4* vp = (const float4*)values + (size_t)(b * S_ + sc * 64) * (H_ / 4) + tid;
  float4 acc = {0.f, 0.f, 0.f, 0.f};
#pragma unroll 4
  for (int i = 0; i < 64; ++i) {
    const float4 v = vp[(size_t)i * (H_ / 4)];
    const float a = a_s[i];
    acc.x += a * v.x; acc.y += a * v.y; acc.z += a * v.z; acc.w += a * v.w;
  }
  ((float4*)part)[(size_t)(b * 32 + sc) * (H_ / 4) + tid] = acc;
}

__global__ void k_ctx_combine(const float* __restrict__ part, float* __restrict__ ctx) {
  const int b = blockIdx.x, tid = threadIdx.x;
  float4 s = {0.f, 0.f, 0.f, 0.f};
#pragma unroll
  for (int c = 0; c < 32; ++c) {
    const float4 v = ((const float4*)part)[(size_t)(b * 32 + c) * (H_ / 4) + tid];
    s.x += v.x; s.y += v.y; s.z += v.z; s.w += v.w;
  }
  ((float4*)ctx)[b * (H_ / 4) + tid] = s;
}

extern "C" void kernel_launch(void* const* d_in, const int* in_sizes, int n_in,
                              void* d_out, int out_size, void* d_ws, size_t ws_size,
                              hipStream_t stream) {
  const float* query  = (const float*)d_in[0];
  const float* values = (const float*)d_in[1];
  const float* W1     = (const float*)d_in[2];
  const float* b1     = (const float*)d_in[3];
  const float* W2     = (const float*)d_in[4];
  const float* b2     = (const float*)d_in[5];
  const float* V      = (const float*)d_in[6];
  // d_in[7] = bV: softmax shift-invariant, affects neither output -> unused.

  char* ws = (char*)d_ws;
  unsigned short* W1T = (unsigned short*)ws;                                   // 2 MB  [U][H] bf16
  float* b1q   = (float*)(ws + 2u * 1024u * 1024u);                            // 128 KB [B][U]
  float* spart = (float*)(ws + 2u * 1024u * 1024u + 128u * 1024u);             // 1 MB  [4][B*S]
  float* qpart = (float*)(ws + 3u * 1024u * 1024u + 128u * 1024u);             // 1 MB  [8][B][U]
  float* cpart = (float*)(ws + 4u * 1024u * 1024u + 256u * 1024u);             // 4 MB  [B*32][H]

  float* aw  = (float*)d_out;        // [B,S,1]
  float* ctx = aw + B_ * S_;         // [B,H]

  k_transpose_w1<<<dim3(16, 16), dim3(64, 4), 0, stream>>>(W1, W1T);
  k_b1q_part<<<dim3(4, 8), dim3(256), 0, stream>>>(query, W2, qpart);
  k_b1q_comb<<<dim3(4, 32), dim3(256), 0, stream>>>(qpart, b1, b2, b1q);
  k_fused_score<<<dim3(2048), dim3(512), 0, stream>>>(values, W1T, b1q, V, spart);
  k_softmax<<<dim3(32), dim3(256), 0, stream>>>(spart, aw);
  k_ctx_partial<<<dim3(32, 32), dim3(256), 0, stream>>>(values, aw, cpart);
  k_ctx_combine<<<dim3(32), dim3(256), 0, stream>>>(cpart, ctx);
}